// Round 1
// baseline (861.898 us; speedup 1.0000x reference)
//
#include <hip/hip_runtime.h>
#include <math.h>

#define NA 10000
#define NE 150000
#define NB 128
#define NRBF 20
#define CUT 5.0f
#define EPSV 1e-8f
#define NBATCH 64
#define CAP 96
#define PI_F 3.14159265358979323846f

__device__ __forceinline__ float silu_f(float x) { return x / (1.0f + expf(-x)); }

// ---------------- init q = emb[atomic_numbers] ----------------
__global__ void init_q_k(const float* __restrict__ emb, const int* __restrict__ z,
                         float* __restrict__ q) {
    int idx = blockIdx.x * blockDim.x + threadIdx.x;
    if (idx >= NA * NB) return;
    int a = idx >> 7, c = idx & 127;
    q[idx] = emb[z[a] * NB + c];
}

// ---------------- edge geometry + phi + bucket build ----------------
__global__ void edge_geom_k(const float* __restrict__ pos,
                            const int* __restrict__ idx_i, const int* __restrict__ idx_j,
                            float* __restrict__ edata, int* __restrict__ cnt,
                            int* __restrict__ bucket) {
    int e = blockIdx.x * blockDim.x + threadIdx.x;
    if (e >= NE) return;
    int i = idx_i[e], j = idx_j[e];
    float rx = pos[j * 3 + 0] - pos[i * 3 + 0];
    float ry = pos[j * 3 + 1] - pos[i * 3 + 1];
    float rz = pos[j * 3 + 2] - pos[i * 3 + 2];
    float d = sqrtf(rx * rx + ry * ry + rz * rz);
    float inv = 1.0f / d;
    float fc = (d < CUT) ? 0.5f * (cosf(d * PI_F / CUT) + 1.0f) : 0.0f;
    float* ed = edata + (size_t)e * 24;
    ed[0] = rx * inv; ed[1] = ry * inv; ed[2] = rz * inv; ed[3] = fc;
    const float width = CUT / (float)(NRBF - 1);
    const float coeff = -0.5f / (width * width);
    #pragma unroll
    for (int k = 0; k < NRBF; k++) {
        float t = d - (float)k * width;
        ed[4 + k] = expf(coeff * t * t);
    }
    int slot = atomicAdd(&cnt[i], 1);
    if (slot < CAP) bucket[i * CAP + slot] = e;
}

// ---------------- x_atom = silu(q@W1+b1)@W2+b2   (8 atoms / 256-thr block) ----------------
__global__ __launch_bounds__(256) void atom_mlp1_k(
    const float* __restrict__ q,
    const float* __restrict__ W1, const float* __restrict__ b1,
    const float* __restrict__ W2, const float* __restrict__ b2,
    float* __restrict__ x_atom) {
    __shared__ float qs[8][132];
    __shared__ float hs[8][132];
    int t = threadIdx.x;
    int abase = blockIdx.x * 8;
    for (int s = 0; s < 4; s++) {
        int idx = t + s * 256;
        int a = idx >> 7, c = idx & 127;
        int ga = abase + a;
        qs[a][c] = (ga < NA) ? q[ga * NB + c] : 0.0f;
    }
    __syncthreads();
    int o = t & 127, g = t >> 7;
    float acc[4] = {0.f, 0.f, 0.f, 0.f};
    for (int k = 0; k < NB; k++) {
        float w = W1[k * NB + o];
        #pragma unroll
        for (int r = 0; r < 4; r++) acc[r] += qs[g * 4 + r][k] * w;
    }
    float bb = b1[o];
    #pragma unroll
    for (int r = 0; r < 4; r++) hs[g * 4 + r][o] = silu_f(acc[r] + bb);
    __syncthreads();
    float acc2[3][4];
    #pragma unroll
    for (int oc = 0; oc < 3; oc++)
        #pragma unroll
        for (int r = 0; r < 4; r++) acc2[oc][r] = 0.f;
    for (int k = 0; k < NB; k++) {
        float h0 = hs[g * 4 + 0][k], h1 = hs[g * 4 + 1][k];
        float h2 = hs[g * 4 + 2][k], h3 = hs[g * 4 + 3][k];
        #pragma unroll
        for (int oc = 0; oc < 3; oc++) {
            float w = W2[k * 384 + oc * 128 + o];
            acc2[oc][0] += h0 * w; acc2[oc][1] += h1 * w;
            acc2[oc][2] += h2 * w; acc2[oc][3] += h3 * w;
        }
    }
    #pragma unroll
    for (int oc = 0; oc < 3; oc++) {
        float bb2 = b2[oc * 128 + o];
        #pragma unroll
        for (int r = 0; r < 4; r++) {
            int ga = abase + g * 4 + r;
            if (ga < NA) x_atom[(size_t)ga * 384 + oc * 128 + o] = acc2[oc][r] + bb2;
        }
    }
}

// ---------------- per-atom edge reduction (no atomics) ----------------
__global__ __launch_bounds__(128) void edge_gather_k(
    const float* __restrict__ fW, const float* __restrict__ fb,
    const float* __restrict__ x_atom, const float* __restrict__ mu,
    const float* __restrict__ edata, const int* __restrict__ cnt,
    const int* __restrict__ bucket, const int* __restrict__ idx_j, int it,
    float* __restrict__ dqb, float* __restrict__ dmub) {
    int a = blockIdx.x;
    int c = threadIdx.x;
    int n = cnt[a]; if (n > CAP) n = CAP;
    float adq = 0.f, admu0 = 0.f, admu1 = 0.f, admu2 = 0.f;
    int colbase = it * 384;
    for (int ei = 0; ei < n; ei++) {
        int e = bucket[a * CAP + ei];
        e = __builtin_amdgcn_readfirstlane(e);
        const float* ed = edata + (size_t)e * 24;
        float dx = ed[0], dy = ed[1], dz = ed[2], fc = ed[3];
        float ph[NRBF];
        #pragma unroll
        for (int k = 0; k < NRBF; k++) ph[k] = ed[4 + k];
        int j = idx_j[e];
        float f0 = 0.f, f1 = 0.f, f2 = 0.f;
        #pragma unroll
        for (int k = 0; k < NRBF; k++) {
            const float* fr = fW + k * 1152 + colbase;
            f0 += ph[k] * fr[c];
            f1 += ph[k] * fr[128 + c];
            f2 += ph[k] * fr[256 + c];
        }
        f0 = (f0 + fb[colbase + c]) * fc;
        f1 = (f1 + fb[colbase + 128 + c]) * fc;
        f2 = (f2 + fb[colbase + 256 + c]) * fc;
        const float* xj = x_atom + (size_t)j * 384;
        float x0 = f0 * xj[c], x1 = f1 * xj[128 + c], x2 = f2 * xj[256 + c];
        adq += x0;
        const float* mj = mu + (size_t)j * 384;
        admu0 += x1 * dx + x2 * mj[c];
        admu1 += x1 * dy + x2 * mj[128 + c];
        admu2 += x1 * dz + x2 * mj[256 + c];
    }
    dqb[a * NB + c] = adq;
    dmub[(size_t)a * 384 + c] = admu0;
    dmub[(size_t)a * 384 + 128 + c] = admu1;
    dmub[(size_t)a * 384 + 256 + c] = admu2;
}

// ---------------- update q,mu; mu_mix; ctx MLP; final update (4 atoms / 256-thr block) ----------------
__global__ __launch_bounds__(256) void ctx_update_k(
    float* __restrict__ q, float* __restrict__ mu,
    const float* __restrict__ dqb, const float* __restrict__ dmub,
    const float* __restrict__ mixW,
    const float* __restrict__ c1W, const float* __restrict__ c1b,
    const float* __restrict__ c2W, const float* __restrict__ c2b) {
    __shared__ float qn[4 * 128];
    __shared__ float mun[4 * 384];
    __shared__ float mm[4 * 768];   // [a][d*256+o]
    __shared__ float ctx[4 * 256];
    __shared__ float hl[4 * 128];
    __shared__ float xl[4 * 384];
    int t = threadIdx.x;
    int abase = blockIdx.x * 4;
    for (int s = 0; s < 2; s++) {
        int idx = t + s * 256; int a = idx >> 7, c = idx & 127; int ga = abase + a;
        qn[idx] = (ga < NA) ? q[ga * NB + c] + dqb[ga * NB + c] : 0.f;
    }
    for (int s = 0; s < 6; s++) {
        int idx = t + s * 256; int a = idx / 384, r = idx % 384; int ga = abase + a;
        mun[idx] = (ga < NA) ? mu[(size_t)ga * 384 + r] + dmub[(size_t)ga * 384 + r] : 0.f;
    }
    __syncthreads();
    {   // mu_mix: o = t in [0,256)
        int o = t;
        for (int a = 0; a < 4; a++) {
            float m0 = 0.f, m1 = 0.f, m2 = 0.f;
            for (int cc = 0; cc < 128; cc++) {
                float w = mixW[cc * 256 + o];
                m0 += mun[a * 384 + cc] * w;
                m1 += mun[a * 384 + 128 + cc] * w;
                m2 += mun[a * 384 + 256 + cc] * w;
            }
            mm[a * 768 + o] = m0; mm[a * 768 + 256 + o] = m1; mm[a * 768 + 512 + o] = m2;
        }
    }
    __syncthreads();
    if (t < 128) {
        int c = t;
        for (int a = 0; a < 4; a++) {
            float v0 = mm[a * 768 + c], v1 = mm[a * 768 + 256 + c], v2 = mm[a * 768 + 512 + c];
            ctx[a * 256 + 128 + c] = sqrtf(v0 * v0 + v1 * v1 + v2 * v2 + EPSV);
            ctx[a * 256 + c] = qn[a * 128 + c];
        }
    }
    __syncthreads();
    {   // hidden = silu(ctx @ c1W + c1b)
        int o = t & 127, g = t >> 7;
        float acc0 = 0.f, acc1 = 0.f;
        for (int k = 0; k < 256; k++) {
            float w = c1W[k * 128 + o];
            acc0 += ctx[(g * 2 + 0) * 256 + k] * w;
            acc1 += ctx[(g * 2 + 1) * 256 + k] * w;
        }
        float bb = c1b[o];
        hl[(g * 2 + 0) * 128 + o] = silu_f(acc0 + bb);
        hl[(g * 2 + 1) * 128 + o] = silu_f(acc1 + bb);
    }
    __syncthreads();
    {   // x = hidden @ c2W + c2b
        int o = t & 127, g = t >> 7;
        float acc[3][2];
        #pragma unroll
        for (int oc = 0; oc < 3; oc++) { acc[oc][0] = 0.f; acc[oc][1] = 0.f; }
        for (int k = 0; k < 128; k++) {
            float h0 = hl[(g * 2 + 0) * 128 + k], h1 = hl[(g * 2 + 1) * 128 + k];
            #pragma unroll
            for (int oc = 0; oc < 3; oc++) {
                float w = c2W[k * 384 + oc * 128 + o];
                acc[oc][0] += h0 * w; acc[oc][1] += h1 * w;
            }
        }
        #pragma unroll
        for (int oc = 0; oc < 3; oc++) {
            float bb = c2b[oc * 128 + o];
            xl[(g * 2 + 0) * 384 + oc * 128 + o] = acc[oc][0] + bb;
            xl[(g * 2 + 1) * 384 + oc * 128 + o] = acc[oc][1] + bb;
        }
    }
    __syncthreads();
    if (t < 128) {
        int c = t;
        for (int a = 0; a < 4; a++) {
            int ga = abase + a; if (ga >= NA) break;
            float v0 = mm[a * 768 + c], v1 = mm[a * 768 + 256 + c], v2 = mm[a * 768 + 512 + c];
            float w0 = mm[a * 768 + 128 + c], w1 = mm[a * 768 + 384 + c], w2 = mm[a * 768 + 640 + c];
            float dot = v0 * w0 + v1 * w1 + v2 * w2;
            float qf = qn[a * 128 + c] + xl[a * 384 + c] + xl[a * 384 + 256 + c] * dot;
            q[ga * NB + c] = qf;
            float dmi = xl[a * 384 + 128 + c];
            mu[(size_t)ga * 384 + c]       = mun[a * 384 + c]       + dmi * w0;
            mu[(size_t)ga * 384 + 128 + c] = mun[a * 384 + 128 + c] + dmi * w1;
            mu[(size_t)ga * 384 + 256 + c] = mun[a * 384 + 256 + c] + dmi * w2;
        }
    }
}

// ---------------- readout MLP + batch segment sum ----------------
__global__ __launch_bounds__(128) void readout_k(
    const float* __restrict__ q,
    const float* __restrict__ o1W, const float* __restrict__ o1b,
    const float* __restrict__ o2W, const float* __restrict__ o2b,
    const float* __restrict__ o3W, const float* __restrict__ o3b,
    const int* __restrict__ idx_m, float* __restrict__ y) {
    __shared__ float qs[4 * 128];
    __shared__ float hs[4 * 128];
    __shared__ float red[128];
    int t = threadIdx.x; int abase = blockIdx.x * 4;
    for (int s = 0; s < 4; s++) {
        int idx = t + s * 128; int a = idx >> 7, c = idx & 127; int ga = abase + a;
        qs[idx] = (ga < NA) ? q[ga * NB + c] : 0.f;
    }
    __syncthreads();
    {
        float acc[4] = {0.f, 0.f, 0.f, 0.f};
        for (int k = 0; k < 128; k++) {
            float w = o1W[k * 128 + t];
            #pragma unroll
            for (int a = 0; a < 4; a++) acc[a] += qs[a * 128 + k] * w;
        }
        float bb = o1b[t];
        #pragma unroll
        for (int a = 0; a < 4; a++) hs[a * 128 + t] = silu_f(acc[a] + bb);
    }
    __syncthreads();
    {
        float acc[4] = {0.f, 0.f, 0.f, 0.f};
        for (int k = 0; k < 128; k++) {
            float w = o2W[k * 128 + t];
            #pragma unroll
            for (int a = 0; a < 4; a++) acc[a] += hs[a * 128 + k] * w;
        }
        float bb = o2b[t];
        __syncthreads();
        #pragma unroll
        for (int a = 0; a < 4; a++) hs[a * 128 + t] = silu_f(acc[a] + bb);
    }
    __syncthreads();
    float w3 = o3W[t];
    for (int a = 0; a < 4; a++) {
        int ga = abase + a; if (ga >= NA) break;
        red[t] = hs[a * 128 + t] * w3;
        __syncthreads();
        for (int off = 64; off > 0; off >>= 1) {
            if (t < off) red[t] += red[t + off];
            __syncthreads();
        }
        if (t == 0) atomicAdd(&y[idx_m[ga]], red[0] + o3b[0]);
        __syncthreads();
    }
}

extern "C" void kernel_launch(void* const* d_in, const int* in_sizes, int n_in,
                              void* d_out, int out_size, void* d_ws, size_t ws_size,
                              hipStream_t stream) {
    const float* pos  = (const float*)d_in[0];
    const float* emb  = (const float*)d_in[1];
    const float* fW   = (const float*)d_in[2];
    const float* fb   = (const float*)d_in[3];
    const float* ic1W = (const float*)d_in[4];
    const float* ic1b = (const float*)d_in[5];
    const float* ic2W = (const float*)d_in[6];
    const float* ic2b = (const float*)d_in[7];
    const float* mixW = (const float*)d_in[8];
    const float* c1W  = (const float*)d_in[9];
    const float* c1b  = (const float*)d_in[10];
    const float* c2W  = (const float*)d_in[11];
    const float* c2b  = (const float*)d_in[12];
    const float* o1W  = (const float*)d_in[13];
    const float* o1b  = (const float*)d_in[14];
    const float* o2W  = (const float*)d_in[15];
    const float* o2b  = (const float*)d_in[16];
    const float* o3W  = (const float*)d_in[17];
    const float* o3b  = (const float*)d_in[18];
    const int* zn     = (const int*)d_in[19];
    const int* idx_i  = (const int*)d_in[20];
    const int* idx_j  = (const int*)d_in[21];
    const int* idx_m  = (const int*)d_in[22];

    float* y  = (float*)d_out;          // 64 outputs
    float* mu = (float*)d_out + NBATCH; // (NA,3,128) accumulated in-place

    char* wp = (char*)d_ws;
    float* q      = (float*)wp; wp += (size_t)NA * NB * 4;
    float* x_atom = (float*)wp; wp += (size_t)NA * 384 * 4;
    float* dqb    = (float*)wp; wp += (size_t)NA * NB * 4;
    float* dmub   = (float*)wp; wp += (size_t)NA * 384 * 4;
    float* edata  = (float*)wp; wp += (size_t)NE * 24 * 4;
    int*   cnt    = (int*)wp;   wp += (size_t)NA * 4;
    int*   bucket = (int*)wp;   wp += (size_t)NA * CAP * 4;

    hipMemsetAsync(d_out, 0, (size_t)(NBATCH + (size_t)NA * 384) * 4, stream);
    hipMemsetAsync(cnt, 0, (size_t)NA * 4, stream);

    init_q_k<<<(NA * NB + 255) / 256, 256, 0, stream>>>(emb, zn, q);
    edge_geom_k<<<(NE + 255) / 256, 256, 0, stream>>>(pos, idx_i, idx_j, edata, cnt, bucket);

    for (int it = 0; it < 3; it++) {
        atom_mlp1_k<<<(NA + 7) / 8, 256, 0, stream>>>(
            q, ic1W + (size_t)it * NB * NB, ic1b + (size_t)it * NB,
            ic2W + (size_t)it * NB * 384, ic2b + (size_t)it * 384, x_atom);
        edge_gather_k<<<NA, 128, 0, stream>>>(
            fW, fb, x_atom, mu, edata, cnt, bucket, idx_j, it, dqb, dmub);
        ctx_update_k<<<(NA + 3) / 4, 256, 0, stream>>>(
            q, mu, dqb, dmub, mixW + (size_t)it * NB * 256,
            c1W + (size_t)it * 256 * NB, c1b + (size_t)it * NB,
            c2W + (size_t)it * NB * 384, c2b + (size_t)it * 384);
    }

    readout_k<<<(NA + 3) / 4, 128, 0, stream>>>(
        q, o1W, o1b, o2W, o2b, o3W, o3b, idx_m, y);
}

// Round 2
// 608.807 us; speedup vs baseline: 1.4157x; 1.4157x over previous
//
#include <hip/hip_runtime.h>
#include <math.h>

#define NA 10000
#define NE 150000
#define NRBF 20
#define CUT 5.0f
#define EPSV 1e-8f
#define NBATCH 64
#define CAP 64
#define PI_F 3.14159265358979323846f

typedef short bf16x8 __attribute__((ext_vector_type(8)));
typedef float f32x4 __attribute__((ext_vector_type(4)));
typedef unsigned short u16;

__device__ __forceinline__ u16 f2b(float x) {
    unsigned u = __builtin_bit_cast(unsigned, x);
    return (u16)((u + 0x7FFFu + ((u >> 16) & 1u)) >> 16);
}
__device__ __forceinline__ float b2f(u16 b) {
    unsigned u = ((unsigned)b) << 16;
    return __builtin_bit_cast(float, u);
}
__device__ __forceinline__ float silu_f(float x) { return x / (1.0f + expf(-x)); }

// packed-weight offsets (in u16 elements)
#define P_IC1 0
#define P_IC2 49152
#define P_MIX 196608
#define P_C1  294912
#define P_C2  393216
#define P_O1  540672
#define P_O2  557056
#define P_TOT 573440

// ---- pack all GEMM weights f32 -> bf16 MFMA B-fragment layout ----
// tile (kb,nb) covers K rows [kb*32,+32), N cols [nb*16,+16).
// frag: lane l, val v = W[kb*32 + 8*(l>>4) + v][nb*16 + (l&15)], stored at
// dst[(kb*NBT+nb)*512 + l*8 + v]  -> GEMM-side b-frag = one 16B coalesced load.
__global__ __launch_bounds__(64) void pack_k(
    const float* __restrict__ ic1W, const float* __restrict__ ic2W,
    const float* __restrict__ mixW, const float* __restrict__ c1W,
    const float* __restrict__ c2W, const float* __restrict__ o1W,
    const float* __restrict__ o2W, u16* __restrict__ packs) {
    int id = blockIdx.x;
    const float* src; u16* dst; int N, rel;
    if (id < 96)        { int m = id / 32;          rel = id % 32; src = ic1W + m * 16384; dst = packs + P_IC1 + m * 16384; N = 128; }
    else if (id < 384)  { id -= 96;  int m = id / 96; rel = id % 96; src = ic2W + m * 49152; dst = packs + P_IC2 + m * 49152; N = 384; }
    else if (id < 576)  { id -= 384; int m = id / 64; rel = id % 64; src = mixW + m * 32768; dst = packs + P_MIX + m * 32768; N = 256; }
    else if (id < 768)  { id -= 576; int m = id / 64; rel = id % 64; src = c1W  + m * 32768; dst = packs + P_C1  + m * 32768; N = 128; }
    else if (id < 1056) { id -= 768; int m = id / 96; rel = id % 96; src = c2W  + m * 49152; dst = packs + P_C2  + m * 49152; N = 384; }
    else if (id < 1088) { rel = id - 1056; src = o1W; dst = packs + P_O1; N = 128; }
    else                { rel = id - 1088; src = o2W; dst = packs + P_O2; N = 128; }
    int NBT = N >> 4;
    int kb = rel / NBT, nb = rel % NBT;
    int l = threadIdx.x;
    int col = nb * 16 + (l & 15);
    int k0 = kb * 32 + 8 * (l >> 4);
    u16 v[8];
    #pragma unroll
    for (int i = 0; i < 8; i++) v[i] = f2b(src[(size_t)(k0 + i) * N + col]);
    *(bf16x8*)(dst + rel * 512 + l * 8) = *(bf16x8*)v;
}

// stage MT x K f32 rows -> LDS bf16 [MT][K+8] (pad: stride%32dw==4 -> 2-way, free)
template<int MT, int K>
__device__ __forceinline__ void stageA(const float* __restrict__ src, int row0,
                                       int maxrow, u16* As) {
    const int NV = MT * K / 4;
    for (int idx = threadIdx.x; idx < NV; idx += 256) {
        int r = idx / (K / 4), c4 = idx % (K / 4);
        float4 v = make_float4(0.f, 0.f, 0.f, 0.f);
        if (row0 + r < maxrow) v = *(const float4*)(src + (size_t)(row0 + r) * K + c4 * 4);
        uint2 o;
        o.x = (unsigned)f2b(v.x) | ((unsigned)f2b(v.y) << 16);
        o.y = (unsigned)f2b(v.z) | ((unsigned)f2b(v.w) << 16);
        *(uint2*)(As + r * (K + 8) + c4 * 4) = o;
    }
}

__device__ __forceinline__ bf16x8 aFrag(const u16* As, int stride, int row, int k0) {
    return *(const bf16x8*)(As + row * stride + k0);
}
__device__ __forceinline__ bf16x8 bFrag(const u16* __restrict__ pack, int NBT,
                                        int ks, int nb, int l) {
    return *(const bf16x8*)(pack + ((size_t)(ks * NBT + nb) * 64 + l) * 8);
}
#define MFMA(a, b, c) __builtin_amdgcn_mfma_f32_16x16x32_bf16(a, b, c, 0, 0, 0)

// ---- init q = emb[z] ----
__global__ void init_q_k(const float* __restrict__ emb, const int* __restrict__ z,
                         float* __restrict__ q) {
    int idx = blockIdx.x * blockDim.x + threadIdx.x;
    if (idx >= NA * 128) return;
    int a = idx >> 7, c = idx & 127;
    q[idx] = emb[z[a] * 128 + c];
}

// ---- edge geometry + phi + bucket ----
__global__ void edge_geom_k(const float* __restrict__ pos,
                            const int* __restrict__ idx_i, const int* __restrict__ idx_j,
                            float* __restrict__ edata, int* __restrict__ cnt,
                            int* __restrict__ bucket) {
    int e = blockIdx.x * blockDim.x + threadIdx.x;
    if (e >= NE) return;
    int i = idx_i[e], j = idx_j[e];
    float rx = pos[j * 3 + 0] - pos[i * 3 + 0];
    float ry = pos[j * 3 + 1] - pos[i * 3 + 1];
    float rz = pos[j * 3 + 2] - pos[i * 3 + 2];
    float d = sqrtf(rx * rx + ry * ry + rz * rz);
    float inv = 1.0f / d;
    float fc = (d < CUT) ? 0.5f * (cosf(d * PI_F / CUT) + 1.0f) : 0.0f;
    float* ed = edata + (size_t)e * 24;
    ed[0] = rx * inv; ed[1] = ry * inv; ed[2] = rz * inv; ed[3] = fc;
    const float width = CUT / (float)(NRBF - 1);
    const float coeff = -0.5f / (width * width);
    #pragma unroll
    for (int k = 0; k < NRBF; k++) {
        float t = d - (float)k * width;
        ed[4 + k] = expf(coeff * t * t);
    }
    int slot = atomicAdd(&cnt[i], 1);
    if (slot < CAP) bucket[i * CAP + slot] = e;
}

// ---- x_atom = silu(q@W1+b1)@W2+b2 -> bf16 ----
__global__ __launch_bounds__(256) void mlp1_k(
    const float* __restrict__ q, const u16* __restrict__ pW1, const float* __restrict__ b1,
    const u16* __restrict__ pW2, const float* __restrict__ b2, u16* __restrict__ x_bf) {
    __shared__ u16 As[32 * 136];
    __shared__ u16 Hs[32 * 136];
    int abase = blockIdx.x * 32;
    stageA<32, 128>(q, abase, NA, As);
    __syncthreads();
    int l = threadIdx.x & 63, w = threadIdx.x >> 6, lm = l & 15, lg = l >> 4;
    f32x4 acc[2][2];
    #pragma unroll
    for (int j = 0; j < 2; j++)
        #pragma unroll
        for (int mi = 0; mi < 2; mi++) acc[j][mi] = (f32x4){0.f, 0.f, 0.f, 0.f};
    #pragma unroll
    for (int ks = 0; ks < 4; ks++) {
        bf16x8 a0 = aFrag(As, 136, lm, ks * 32 + 8 * lg);
        bf16x8 a1 = aFrag(As, 136, 16 + lm, ks * 32 + 8 * lg);
        #pragma unroll
        for (int j = 0; j < 2; j++) {
            bf16x8 b = bFrag(pW1, 8, ks, w + 4 * j, l);
            acc[j][0] = MFMA(a0, b, acc[j][0]);
            acc[j][1] = MFMA(a1, b, acc[j][1]);
        }
    }
    #pragma unroll
    for (int j = 0; j < 2; j++) {
        int col = 16 * (w + 4 * j) + lm;
        float bb = b1[col];
        #pragma unroll
        for (int mi = 0; mi < 2; mi++)
            #pragma unroll
            for (int v = 0; v < 4; v++)
                Hs[(16 * mi + 4 * lg + v) * 136 + col] = f2b(silu_f(acc[j][mi][v] + bb));
    }
    __syncthreads();
    f32x4 acc2[6][2];
    #pragma unroll
    for (int j = 0; j < 6; j++)
        #pragma unroll
        for (int mi = 0; mi < 2; mi++) acc2[j][mi] = (f32x4){0.f, 0.f, 0.f, 0.f};
    #pragma unroll
    for (int ks = 0; ks < 4; ks++) {
        bf16x8 a0 = aFrag(Hs, 136, lm, ks * 32 + 8 * lg);
        bf16x8 a1 = aFrag(Hs, 136, 16 + lm, ks * 32 + 8 * lg);
        #pragma unroll
        for (int j = 0; j < 6; j++) {
            bf16x8 b = bFrag(pW2, 24, ks, w + 4 * j, l);
            acc2[j][0] = MFMA(a0, b, acc2[j][0]);
            acc2[j][1] = MFMA(a1, b, acc2[j][1]);
        }
    }
    #pragma unroll
    for (int j = 0; j < 6; j++) {
        int col = 16 * (w + 4 * j) + lm;
        float bb = b2[col];
        #pragma unroll
        for (int mi = 0; mi < 2; mi++)
            #pragma unroll
            for (int v = 0; v < 4; v++) {
                int ga = abase + 16 * mi + 4 * lg + v;
                if (ga < NA) x_bf[(size_t)ga * 384 + col] = f2b(acc2[j][mi][v] + bb);
            }
    }
}

// ---- per-atom edge reduction; updates q,mu masters in place ----
__global__ __launch_bounds__(128) void gather_k(
    const float* __restrict__ fW, const float* __restrict__ fb,
    const u16* __restrict__ x_bf, const u16* __restrict__ mu_bf,
    const float* __restrict__ edata, const int* __restrict__ cnt,
    const int* __restrict__ bucket, const int* __restrict__ idx_j, int it,
    float* __restrict__ q, float* __restrict__ muF) {
    int a = blockIdx.x, c = threadIdx.x;
    int cb = it * 384;
    float w0[NRBF], w1[NRBF], w2[NRBF];
    #pragma unroll
    for (int k = 0; k < NRBF; k++) {
        const float* fr = fW + k * 1152 + cb;
        w0[k] = fr[c]; w1[k] = fr[128 + c]; w2[k] = fr[256 + c];
    }
    float fb0 = fb[cb + c], fb1 = fb[cb + 128 + c], fb2 = fb[cb + 256 + c];
    int n = cnt[a]; if (n > CAP) n = CAP;
    const int* bk = bucket + a * CAP;
    float adq = 0.f, am0 = 0.f, am1 = 0.f, am2 = 0.f;
    for (int ei = 0; ei < n; ei++) {
        int e = __builtin_amdgcn_readfirstlane(bk[ei]);
        const float* ed = edata + (size_t)e * 24;
        float4 g  = *(const float4*)(ed);
        float4 p0 = *(const float4*)(ed + 4);
        float4 p1 = *(const float4*)(ed + 8);
        float4 p2 = *(const float4*)(ed + 12);
        float4 p3 = *(const float4*)(ed + 16);
        float4 p4 = *(const float4*)(ed + 20);
        float ph[NRBF] = {p0.x, p0.y, p0.z, p0.w, p1.x, p1.y, p1.z, p1.w,
                          p2.x, p2.y, p2.z, p2.w, p3.x, p3.y, p3.z, p3.w,
                          p4.x, p4.y, p4.z, p4.w};
        float f0 = fb0, f1 = fb1, f2 = fb2;
        #pragma unroll
        for (int k = 0; k < NRBF; k++) {
            f0 += ph[k] * w0[k]; f1 += ph[k] * w1[k]; f2 += ph[k] * w2[k];
        }
        f0 *= g.w; f1 *= g.w; f2 *= g.w;
        int j = idx_j[e];
        const u16* xr = x_bf + (size_t)j * 384;
        const u16* mr = mu_bf + (size_t)j * 384;
        float x0 = f0 * b2f(xr[c]), x1 = f1 * b2f(xr[128 + c]), x2 = f2 * b2f(xr[256 + c]);
        adq += x0;
        am0 += x1 * g.x + x2 * b2f(mr[c]);
        am1 += x1 * g.y + x2 * b2f(mr[128 + c]);
        am2 += x1 * g.z + x2 * b2f(mr[256 + c]);
    }
    q[(size_t)a * 128 + c] += adq;
    muF[(size_t)a * 384 + c] += am0;
    muF[(size_t)a * 384 + 128 + c] += am1;
    muF[(size_t)a * 384 + 256 + c] += am2;
}

// ---- mu_mix: (3*NA x 128) @ (128 x 256) -> mm bf16 ----
__global__ __launch_bounds__(256) void mix_k(
    const float* __restrict__ muF, const u16* __restrict__ pM, u16* __restrict__ mm) {
    __shared__ u16 As[96 * 136];
    int rbase = blockIdx.x * 96;
    stageA<96, 128>(muF, rbase, 3 * NA, As);
    __syncthreads();
    int l = threadIdx.x & 63, w = threadIdx.x >> 6, lm = l & 15, lg = l >> 4;
    f32x4 acc[4][6];
    #pragma unroll
    for (int j = 0; j < 4; j++)
        #pragma unroll
        for (int mi = 0; mi < 6; mi++) acc[j][mi] = (f32x4){0.f, 0.f, 0.f, 0.f};
    #pragma unroll
    for (int ks = 0; ks < 4; ks++) {
        bf16x8 a[6];
        #pragma unroll
        for (int mi = 0; mi < 6; mi++) a[mi] = aFrag(As, 136, 16 * mi + lm, ks * 32 + 8 * lg);
        #pragma unroll
        for (int j = 0; j < 4; j++) {
            bf16x8 b = bFrag(pM, 16, ks, w + 4 * j, l);
            #pragma unroll
            for (int mi = 0; mi < 6; mi++) acc[j][mi] = MFMA(a[mi], b, acc[j][mi]);
        }
    }
    #pragma unroll
    for (int j = 0; j < 4; j++) {
        int col = 16 * (w + 4 * j) + lm;
        #pragma unroll
        for (int mi = 0; mi < 6; mi++)
            #pragma unroll
            for (int v = 0; v < 4; v++) {
                int R = rbase + 16 * mi + 4 * lg + v;
                if (R < 3 * NA) mm[(size_t)R * 256 + col] = f2b(acc[j][mi][v]);
            }
    }
}

// ---- ctx MLP + final q/mu update ----
__global__ __launch_bounds__(256) void ctx_k(
    float* __restrict__ q, const u16* __restrict__ mm, float* __restrict__ muF,
    u16* __restrict__ mu_bf,
    const u16* __restrict__ pC1, const float* __restrict__ c1b,
    const u16* __restrict__ pC2, const float* __restrict__ c2b) {
    __shared__ u16 As[32 * 264];
    __shared__ u16 Hs[32 * 136];
    int abase = blockIdx.x * 32;
    for (int idx = threadIdx.x; idx < 32 * 128; idx += 256) {
        int a = idx >> 7, c = idx & 127;
        int ga = abase + a;
        float qv = 0.f, s = EPSV;
        if (ga < NA) {
            qv = q[(size_t)ga * 128 + c];
            #pragma unroll
            for (int d = 0; d < 3; d++) {
                float t = b2f(mm[((size_t)ga * 3 + d) * 256 + c]);
                s += t * t;
            }
        }
        As[a * 264 + c] = f2b(qv);
        As[a * 264 + 128 + c] = f2b(sqrtf(s));
    }
    __syncthreads();
    int l = threadIdx.x & 63, w = threadIdx.x >> 6, lm = l & 15, lg = l >> 4;
    f32x4 acc[2][2];
    #pragma unroll
    for (int j = 0; j < 2; j++)
        #pragma unroll
        for (int mi = 0; mi < 2; mi++) acc[j][mi] = (f32x4){0.f, 0.f, 0.f, 0.f};
    #pragma unroll
    for (int ks = 0; ks < 8; ks++) {
        bf16x8 a0 = aFrag(As, 264, lm, ks * 32 + 8 * lg);
        bf16x8 a1 = aFrag(As, 264, 16 + lm, ks * 32 + 8 * lg);
        #pragma unroll
        for (int j = 0; j < 2; j++) {
            bf16x8 b = bFrag(pC1, 8, ks, w + 4 * j, l);
            acc[j][0] = MFMA(a0, b, acc[j][0]);
            acc[j][1] = MFMA(a1, b, acc[j][1]);
        }
    }
    #pragma unroll
    for (int j = 0; j < 2; j++) {
        int col = 16 * (w + 4 * j) + lm;
        float bb = c1b[col];
        #pragma unroll
        for (int mi = 0; mi < 2; mi++)
            #pragma unroll
            for (int v = 0; v < 4; v++)
                Hs[(16 * mi + 4 * lg + v) * 136 + col] = f2b(silu_f(acc[j][mi][v] + bb));
    }
    __syncthreads();
    f32x4 acc2[6][2];
    #pragma unroll
    for (int j = 0; j < 6; j++)
        #pragma unroll
        for (int mi = 0; mi < 2; mi++) acc2[j][mi] = (f32x4){0.f, 0.f, 0.f, 0.f};
    #pragma unroll
    for (int ks = 0; ks < 4; ks++) {
        bf16x8 a0 = aFrag(Hs, 136, lm, ks * 32 + 8 * lg);
        bf16x8 a1 = aFrag(Hs, 136, 16 + lm, ks * 32 + 8 * lg);
        #pragma unroll
        for (int j = 0; j < 6; j++) {
            bf16x8 b = bFrag(pC2, 24, ks, w + 4 * j, l);
            acc2[j][0] = MFMA(a0, b, acc2[j][0]);
            acc2[j][1] = MFMA(a1, b, acc2[j][1]);
        }
    }
    #pragma unroll
    for (int j = 0; j < 6; j++) {
        int col = 16 * (w + 4 * j) + lm;
        float bb = c2b[col];
        #pragma unroll
        for (int mi = 0; mi < 2; mi++)
            #pragma unroll
            for (int v = 0; v < 4; v++) acc2[j][mi][v] += bb;
    }
    #pragma unroll
    for (int mi = 0; mi < 2; mi++)
        #pragma unroll
        for (int v = 0; v < 4; v++) {
            int ga = abase + 16 * mi + 4 * lg + v;
            if (ga >= NA) continue;
            #pragma unroll
            for (int jj = 0; jj < 2; jj++) {
                int c = 16 * w + 64 * jj + lm;
                float x0 = acc2[jj][mi][v], x1 = acc2[jj + 2][mi][v], x2 = acc2[jj + 4][mi][v];
                float dot = 0.f, muW[3];
                #pragma unroll
                for (int d = 0; d < 3; d++) {
                    float muV = b2f(mm[((size_t)ga * 3 + d) * 256 + c]);
                    muW[d] = b2f(mm[((size_t)ga * 3 + d) * 256 + 128 + c]);
                    dot += muV * muW[d];
                }
                q[(size_t)ga * 128 + c] += x0 + x2 * dot;
                #pragma unroll
                for (int d = 0; d < 3; d++) {
                    size_t mo = (size_t)ga * 384 + d * 128 + c;
                    float m = muF[mo] + x1 * muW[d];
                    muF[mo] = m;
                    mu_bf[mo] = f2b(m);
                }
            }
        }
}

// ---- readout: silu(silu(q@o1)@o2)@o3 + segment-sum ----
__global__ __launch_bounds__(256) void readout_k(
    const float* __restrict__ q, const u16* __restrict__ pO1, const float* __restrict__ o1b,
    const u16* __restrict__ pO2, const float* __restrict__ o2b,
    const float* __restrict__ o3W, const float* __restrict__ o3b,
    const int* __restrict__ idx_m, float* __restrict__ y) {
    __shared__ u16 As[32 * 136];
    __shared__ u16 Hs[32 * 136];
    __shared__ float red[256];
    int abase = blockIdx.x * 32;
    stageA<32, 128>(q, abase, NA, As);
    __syncthreads();
    int l = threadIdx.x & 63, w = threadIdx.x >> 6, lm = l & 15, lg = l >> 4;
    f32x4 acc[2][2];
    #pragma unroll
    for (int j = 0; j < 2; j++)
        #pragma unroll
        for (int mi = 0; mi < 2; mi++) acc[j][mi] = (f32x4){0.f, 0.f, 0.f, 0.f};
    #pragma unroll
    for (int ks = 0; ks < 4; ks++) {
        bf16x8 a0 = aFrag(As, 136, lm, ks * 32 + 8 * lg);
        bf16x8 a1 = aFrag(As, 136, 16 + lm, ks * 32 + 8 * lg);
        #pragma unroll
        for (int j = 0; j < 2; j++) {
            bf16x8 b = bFrag(pO1, 8, ks, w + 4 * j, l);
            acc[j][0] = MFMA(a0, b, acc[j][0]);
            acc[j][1] = MFMA(a1, b, acc[j][1]);
        }
    }
    #pragma unroll
    for (int j = 0; j < 2; j++) {
        int col = 16 * (w + 4 * j) + lm;
        float bb = o1b[col];
        #pragma unroll
        for (int mi = 0; mi < 2; mi++)
            #pragma unroll
            for (int v = 0; v < 4; v++)
                Hs[(16 * mi + 4 * lg + v) * 136 + col] = f2b(silu_f(acc[j][mi][v] + bb));
    }
    __syncthreads();
    f32x4 acc2[2][2];
    #pragma unroll
    for (int j = 0; j < 2; j++)
        #pragma unroll
        for (int mi = 0; mi < 2; mi++) acc2[j][mi] = (f32x4){0.f, 0.f, 0.f, 0.f};
    #pragma unroll
    for (int ks = 0; ks < 4; ks++) {
        bf16x8 a0 = aFrag(Hs, 136, lm, ks * 32 + 8 * lg);
        bf16x8 a1 = aFrag(Hs, 136, 16 + lm, ks * 32 + 8 * lg);
        #pragma unroll
        for (int j = 0; j < 2; j++) {
            bf16x8 b = bFrag(pO2, 8, ks, w + 4 * j, l);
            acc2[j][0] = MFMA(a0, b, acc2[j][0]);
            acc2[j][1] = MFMA(a1, b, acc2[j][1]);
        }
    }
    #pragma unroll
    for (int j = 0; j < 2; j++) {
        int col = 16 * (w + 4 * j) + lm;
        float bb = o2b[col];
        #pragma unroll
        for (int mi = 0; mi < 2; mi++)
            #pragma unroll
            for (int v = 0; v < 4; v++)
                As[(16 * mi + 4 * lg + v) * 136 + col] = f2b(silu_f(acc2[j][mi][v] + bb));
    }
    __syncthreads();
    int a = threadIdx.x >> 3, gseg = threadIdx.x & 7;
    float p = 0.f;
    #pragma unroll
    for (int cc = 0; cc < 16; cc++) {
        int c = gseg * 16 + cc;
        p += b2f(As[a * 136 + c]) * o3W[c];
    }
    red[threadIdx.x] = p;
    __syncthreads();
    if (gseg == 0) {
        float s = 0.f;
        #pragma unroll
        for (int k = 0; k < 8; k++) s += red[a * 8 + k];
        int ga = abase + a;
        if (ga < NA) atomicAdd(&y[idx_m[ga]], s + o3b[0]);
    }
}

extern "C" void kernel_launch(void* const* d_in, const int* in_sizes, int n_in,
                              void* d_out, int out_size, void* d_ws, size_t ws_size,
                              hipStream_t stream) {
    const float* pos  = (const float*)d_in[0];
    const float* emb  = (const float*)d_in[1];
    const float* fW   = (const float*)d_in[2];
    const float* fb   = (const float*)d_in[3];
    const float* ic1W = (const float*)d_in[4];
    const float* ic1b = (const float*)d_in[5];
    const float* ic2W = (const float*)d_in[6];
    const float* ic2b = (const float*)d_in[7];
    const float* mixW = (const float*)d_in[8];
    const float* c1W  = (const float*)d_in[9];
    const float* c1b  = (const float*)d_in[10];
    const float* c2W  = (const float*)d_in[11];
    const float* c2b  = (const float*)d_in[12];
    const float* o1W  = (const float*)d_in[13];
    const float* o1b  = (const float*)d_in[14];
    const float* o2W  = (const float*)d_in[15];
    const float* o2b  = (const float*)d_in[16];
    const float* o3W  = (const float*)d_in[17];
    const float* o3b  = (const float*)d_in[18];
    const int* zn     = (const int*)d_in[19];
    const int* idx_i  = (const int*)d_in[20];
    const int* idx_j  = (const int*)d_in[21];
    const int* idx_m  = (const int*)d_in[22];

    float* y   = (float*)d_out;
    float* muF = (float*)d_out + NBATCH;  // (NA,3,128) f32 master

    char* wp = (char*)d_ws;
    float* q     = (float*)wp;  wp += (size_t)NA * 128 * 4;        // 5.12 MB
    u16*   x_bf  = (u16*)wp;                                       // x (7.68MB) ...
    u16*   mm    = (u16*)wp;    wp += (size_t)30000 * 256 * 2;     // aliased: mm spans 15.36 MB
    u16*   mu_bf = (u16*)wp;    wp += (size_t)NA * 384 * 2;        // 7.68 MB
    float* edata = (float*)wp;  wp += (size_t)NE * 24 * 4;         // 14.4 MB
    int*   cnt   = (int*)wp;    wp += (size_t)NA * 4;
    int*   bucket= (int*)wp;    wp += (size_t)NA * CAP * 4;        // 2.56 MB
    u16*   packs = (u16*)wp;    wp += (size_t)P_TOT * 2;           // 1.15 MB

    hipMemsetAsync(d_out, 0, (size_t)(NBATCH + (size_t)NA * 384) * 4, stream);
    hipMemsetAsync(cnt, 0, (size_t)NA * 4, stream);
    hipMemsetAsync(mu_bf, 0, (size_t)NA * 384 * 2, stream);

    pack_k<<<1120, 64, 0, stream>>>(ic1W, ic2W, mixW, c1W, c2W, o1W, o2W, packs);
    init_q_k<<<(NA * 128 + 255) / 256, 256, 0, stream>>>(emb, zn, q);
    edge_geom_k<<<(NE + 255) / 256, 256, 0, stream>>>(pos, idx_i, idx_j, edata, cnt, bucket);

    for (int it = 0; it < 3; it++) {
        mlp1_k<<<313, 256, 0, stream>>>(
            q, packs + P_IC1 + it * 16384, ic1b + it * 128,
            packs + P_IC2 + it * 49152, ic2b + it * 384, x_bf);
        gather_k<<<NA, 128, 0, stream>>>(
            fW, fb, x_bf, mu_bf, edata, cnt, bucket, idx_j, it, q, muF);
        mix_k<<<313, 256, 0, stream>>>(muF, packs + P_MIX + it * 32768, mm);
        ctx_k<<<313, 256, 0, stream>>>(
            q, mm, muF, mu_bf,
            packs + P_C1 + it * 32768, c1b + it * 128,
            packs + P_C2 + it * 49152, c2b + it * 384);
    }

    readout_k<<<313, 256, 0, stream>>>(q, packs + P_O1, o1b, packs + P_O2, o2b,
                                       o3W, o3b, idx_m, y);
}